// Round 2
// baseline (778.151 us; speedup 1.0000x reference)
//
#include <hip/hip_runtime.h>
#include <hip/hip_bf16.h>

#define NTOK   49
#define DIM    384
#define KEY_DIM 32
#define HEADS  8
#define D_HEAD 128
#define SCALE  0.17677669529663687f   // 32^-0.5

typedef short short8 __attribute__((ext_vector_type(8)));
typedef short short4_t __attribute__((ext_vector_type(4)));
typedef float f32x4 __attribute__((ext_vector_type(4)));

__device__ __forceinline__ unsigned short f2bf(float x) {
    union { float f; unsigned u; } v; v.f = x;
    unsigned r = v.u + 0x7fffu + ((v.u >> 16) & 1u);   // RNE
    return (unsigned short)(r >> 16);
}

__device__ __forceinline__ f32x4 MFMA(short8 a, short8 b, f32x4 c) {
    return __builtin_amdgcn_mfma_f32_16x16x32_bf16(a, b, c, 0, 0, 0);
}

// ---------------- prologue: weight packing + bias expansion ----------------
// packed chunk layout for weight W[N][K] (row-major, K contig):
//   chunk t = (ntile*KT + ktile)*64 + lane ; elem j: W[ntile*16+(lane&15)][ktile*32+(lane>>4)*8+j]
__global__ void prologue(const float* __restrict__ qw, const float* __restrict__ qb,
                         const float* __restrict__ kw,
                         const float* __restrict__ vw, const float* __restrict__ pw,
                         const float* __restrict__ biases, const int* __restrict__ idxs,
                         int n_off,
                         unsigned short* __restrict__ qk_p,
                         unsigned short* __restrict__ vw_p,
                         unsigned short* __restrict__ pw_p,
                         float* __restrict__ qb_s,
                         float* __restrict__ ab_t) {
    int t = blockIdx.x * 256 + threadIdx.x;
    if (t < 24576) {                       // QK pack: N=512 (Q|K), K=384, KT=12
        int lane = t & 63, kt = (t >> 6) % 12, ntile = t / 768;
        int c = ntile * 16 + (lane & 15), kk = kt * 32 + (lane >> 4) * 8;
        const float* src = (c < 256) ? (qw + c * 384 + kk) : (kw + (c - 256) * 384 + kk);
        float sc = (c < 256) ? SCALE : 1.0f;
        short8 o;
#pragma unroll
        for (int j = 0; j < 8; ++j) o[j] = (short)f2bf(src[j] * sc);
        *(short8*)(qk_p + (size_t)t * 8) = o;
    } else if (t < 73728) {                // V pack: N=1024, K=384, KT=12
        int u = t - 24576;
        int lane = u & 63, kt = (u >> 6) % 12, ntile = u / 768;
        int c = ntile * 16 + (lane & 15), kk = kt * 32 + (lane >> 4) * 8;
        const float* src = vw + c * 384 + kk;
        short8 o;
#pragma unroll
        for (int j = 0; j < 8; ++j) o[j] = (short)f2bf(src[j]);
        *(short8*)(vw_p + (size_t)u * 8) = o;
    } else if (t < 122880) {               // proj pack: N=384, K=1024, KT=32
        int u = t - 73728;
        int lane = u & 63, kt = (u >> 6) % 32, ntile = u / 2048;
        int c = ntile * 16 + (lane & 15), kk = kt * 32 + (lane >> 4) * 8;
        const float* src = pw + c * 1024 + kk;
        short8 o;
#pragma unroll
        for (int j = 0; j < 8; ++j) o[j] = (short)f2bf(src[j]);
        *(short8*)(pw_p + (size_t)u * 8) = o;
    } else if (t < 123136) {               // scaled q bias
        int u = t - 122880;
        qb_s[u] = qb[u] * SCALE;
    } else if (t < 123136 + 32768) {       // ab_t[h][m][n], zero-padded to 64x64
        int u = t - 123136;
        int h = u >> 12, m = (u >> 6) & 63, n = u & 63;
        float v = 0.f;
        if (m < 49 && n < 49) v = biases[h * n_off + idxs[n * 49 + m]];
        ab_t[u] = v;
    }
}

// ---------------- fused attention: one block (8 waves) per batch ----------------
// LDS layout (ushort offsets), total 81,312 B -> 2 blocks/CU:
//   xs  @     0 : [49][392]   x bf16 (A-row reads clamp to row 48)
//   ps  @ 19208 : [49][72]    P bf16 (writes predicated n<49, reads clamped)
//   vsT @ 22736 : [128][72]   V_h^T [d][m]
//   U   @ 31952 : 17,408 B union:
//        qs  = U          [64][40]   (live P0 -> bar B)
//        ks2 = U + 2560   [64][40]
//        osA = U          [64][136]  (live bar B -> bar D)
__global__ __launch_bounds__(512, 4) void fused_attn(
        const float* __restrict__ x,
        const unsigned short* __restrict__ qkw,   // packed [32 nt][12 kt][64][8]
        const unsigned short* __restrict__ vw,    // packed [64 nt][12 kt][64][8]
        const unsigned short* __restrict__ pw,    // packed [24 nt][32 kt][64][8]
        const float* __restrict__ qb_s, const float* __restrict__ kb,
        const float* __restrict__ vb, const float* __restrict__ pb,
        const float* __restrict__ ab_t,           // [8][64][64] f32
        float* __restrict__ out) {

    __shared__ __align__(16) unsigned short smem[40656];   // 81,312 B
    unsigned short* xs  = smem;              // [49][392]
    unsigned short* ps  = smem + 19208;      // [49][72]
    unsigned short* vsT = smem + 22736;      // [128][72]
    unsigned short* qs  = smem + 31952;      // [64][40]
    unsigned short* ks2 = smem + 31952 + 2560; // [64][40]
    unsigned short* osA = smem + 31952;      // [64][136] overlays qs/ks2

    const int tid  = threadIdx.x;
    const int lane = tid & 63;
    const int wid  = tid >> 6;       // 0..7
    const int l15  = lane & 15;
    const int lg   = lane >> 4;      // 0..3
    const int b    = blockIdx.x;

    // ---- stage x -> bf16 LDS (49 rows only; reads clamp) ----
    const float* xb = x + (size_t)b * (NTOK * DIM);
#pragma unroll 2
    for (int i = tid; i < 4704; i += 512) {            // 4704 float4
        float4 v = ((const float4*)xb)[i];
        int f = i * 4;
        int row = f / DIM;
        int col = f - row * DIM;
        short4_t pk;
        pk[0] = (short)f2bf(v.x); pk[1] = (short)f2bf(v.y);
        pk[2] = (short)f2bf(v.z); pk[3] = (short)f2bf(v.w);
        *(short4_t*)&xs[row * 392 + col] = pk;
    }
    __syncthreads();

    f32x4 pacc[3][4];                                   // persistent proj acc
#pragma unroll
    for (int i = 0; i < 3; ++i)
#pragma unroll
        for (int j = 0; j < 4; ++j) pacc[i][j] = (f32x4)0.f;

    const f32x4 zf = (f32x4)0.f;

    for (int h = 0; h < HEADS; ++h) {
        // ================= P0: Q_h,K_h,V_h projection =================
        {
            const int mh  = wid >> 2;          // 0..1 -> rows mh*32..mh*32+31
            const int nt0 = 3 * (wid & 3);     // nt triple, N=192 = 12 nt
            const int rA0 = min(mh * 32 + l15, 48);
            const int rA1 = min(mh * 32 + 16 + l15, 48);
            f32x4 acc[3][2];
#pragma unroll
            for (int i = 0; i < 3; ++i) { acc[i][0] = zf; acc[i][1] = zf; }

            const short8* bptr[3];
#pragma unroll
            for (int i = 0; i < 3; ++i) {
                int nt = nt0 + i;
                const unsigned short* base; int ntile;
                if (nt < 2)      { base = qkw; ntile = 2 * h + nt; }
                else if (nt < 4) { base = qkw; ntile = 16 + 2 * h + (nt - 2); }
                else             { base = vw;  ntile = 8 * h + (nt - 4); }
                bptr[i] = (const short8*)(base + (size_t)ntile * 12 * 64 * 8);
            }
#pragma unroll
            for (int kt = 0; kt < 12; ++kt) {
                short8 a0 = *(const short8*)&xs[rA0 * 392 + kt * 32 + lg * 8];
                short8 a1 = *(const short8*)&xs[rA1 * 392 + kt * 32 + lg * 8];
#pragma unroll
                for (int i = 0; i < 3; ++i) {
                    short8 bf = bptr[i][kt * 64 + lane];
                    acc[i][0] = MFMA(a0, bf, acc[i][0]);
                    acc[i][1] = MFMA(a1, bf, acc[i][1]);
                }
            }
            // epilogue: +bias, ->bf16, scatter to qs/ks/vsT
#pragma unroll
            for (int i = 0; i < 3; ++i) {
                int nt = nt0 + i;
                int c  = nt * 16 + l15;        // 0..191
                if (nt < 4) {                  // Q (c<32) or K (32..63)
                    int cc = (nt < 2) ? c : c - 32;
                    float bias = (nt < 2) ? qb_s[h * 32 + cc] : kb[h * 32 + cc];
                    unsigned short* dst = (nt < 2) ? qs : ks2;
#pragma unroll
                    for (int j = 0; j < 2; ++j) {
                        int r0 = mh * 32 + j * 16 + lg * 4;
                        f32x4 v = acc[i][j];
#pragma unroll
                        for (int r = 0; r < 4; ++r)
                            dst[(r0 + r) * 40 + cc] = f2bf(v[r] + bias);
                    }
                } else {                       // V -> transposed
                    int d = c - 64;            // 0..127
                    float bias = vb[h * 128 + d];
#pragma unroll
                    for (int j = 0; j < 2; ++j) {
                        int m0 = mh * 32 + j * 16 + lg * 4;
                        f32x4 v = acc[i][j];
                        short4_t pk;
#pragma unroll
                        for (int r = 0; r < 4; ++r) pk[r] = (short)f2bf(v[r] + bias);
                        *(short4_t*)&vsT[d * 72 + m0] = pk;
                    }
                }
            }
        }
        __syncthreads();   // bar A: qs/ks/vsT ready

        // ================= P1: S^T = K@Q^T, softmax (waves 0-3) =================
        if (wid < 4) {
            const int I = wid;                 // n-tile
            const int rq = min(I * 16 + l15, 48);
            short8 bq = *(const short8*)&qs[rq * 40 + lg * 8];
            f32x4 s[4];
#pragma unroll
            for (int J = 0; J < 4; ++J) {
                short8 ak = *(const short8*)&ks2[(J * 16 + l15) * 40 + lg * 8];
                s[J] = MFMA(ak, bq, zf);
            }
            const float* abh = ab_t + h * 4096 + I * 16 + l15;  // [m*64 + n]
            float sv[16];
            float mx = -1e30f;
#pragma unroll
            for (int J = 0; J < 4; ++J)
#pragma unroll
                for (int r = 0; r < 4; ++r) {
                    int m = J * 16 + lg * 4 + r;
                    float val = s[J][r] + abh[m * 64];
                    if (m >= 49) val = -1e30f;
                    sv[J * 4 + r] = val;
                    mx = fmaxf(mx, val);
                }
            mx = fmaxf(mx, __shfl_xor(mx, 16));
            mx = fmaxf(mx, __shfl_xor(mx, 32));
            float sum = 0.f;
#pragma unroll
            for (int t = 0; t < 16; ++t) { float e = __expf(sv[t] - mx); sv[t] = e; sum += e; }
            sum += __shfl_xor(sum, 16);
            sum += __shfl_xor(sum, 32);
            float inv = 1.0f / sum;
            int n = I * 16 + l15;
            if (n < 49) {
#pragma unroll
                for (int J = 0; J < 4; ++J)
#pragma unroll
                    for (int r = 0; r < 4; ++r) {
                        int m = J * 16 + lg * 4 + r;
                        ps[n * 72 + m] = f2bf(sv[J * 4 + r] * inv);
                    }
            }
        }
        __syncthreads();   // bar B: ps ready (qs/ks dead -> osA may be written)

        // ================= P2a: O_h = P @ V_h =================
        {
            const int np = wid >> 2;           // n-tile pair
            const int dp = wid & 3;            // d-tile pair
            const int rp0 = min(np * 32 + l15, 48);
            const int rp1 = min(np * 32 + 16 + l15, 48);
            f32x4 a00 = zf, a01 = zf, a10 = zf, a11 = zf;
#pragma unroll
            for (int kk = 0; kk < 2; ++kk) {
                short8 a0 = *(const short8*)&ps[rp0 * 72 + kk * 32 + lg * 8];
                short8 a1 = *(const short8*)&ps[rp1 * 72 + kk * 32 + lg * 8];
                short8 b0 = *(const short8*)&vsT[(dp * 32 + l15) * 72 + kk * 32 + lg * 8];
                short8 b1 = *(const short8*)&vsT[(dp * 32 + 16 + l15) * 72 + kk * 32 + lg * 8];
                a00 = MFMA(a0, b0, a00); a01 = MFMA(a0, b1, a01);
                a10 = MFMA(a1, b0, a10); a11 = MFMA(a1, b1, a11);
            }
            f32x4 accs[2][2] = {{a00, a01}, {a10, a11}};
#pragma unroll
            for (int jn = 0; jn < 2; ++jn)
#pragma unroll
                for (int jd = 0; jd < 2; ++jd) {
                    int r0 = np * 32 + jn * 16 + lg * 4;
                    int d0 = dp * 32 + jd * 16 + l15;
                    f32x4 v = accs[jn][jd];
#pragma unroll
                    for (int r = 0; r < 4; ++r) osA[(r0 + r) * 136 + d0] = f2bf(v[r]);
                }
        }
        __syncthreads();   // bar C: osA ready

        // ================= P2b: out-proj chunk (K = this head's 128) =================
        {
            const int nt0 = 3 * wid;           // 24 nt over 8 waves
#pragma unroll
            for (int kt = 0; kt < 4; ++kt) {
                short8 a[4];
#pragma unroll
                for (int mi = 0; mi < 4; ++mi)
                    a[mi] = *(const short8*)&osA[(mi * 16 + l15) * 136 + kt * 32 + lg * 8];
#pragma unroll
                for (int i = 0; i < 3; ++i) {
                    short8 bf = ((const short8*)pw)[((size_t)(nt0 + i) * 32 + (h * 4 + kt)) * 64 + lane];
#pragma unroll
                    for (int mi = 0; mi < 4; ++mi)
                        pacc[i][mi] = MFMA(a[mi], bf, pacc[i][mi]);
                }
            }
        }
        __syncthreads();   // bar D: safe to overwrite qs/ks/vsT/ps/osA
    }

    // ---- final epilogue: +proj_b, store f32 rows n<49 ----
    float* ob = out + (size_t)b * (NTOK * 384);
#pragma unroll
    for (int i = 0; i < 3; ++i) {
        int c = (3 * wid + i) * 16 + l15;
        float bias = pb[c];
#pragma unroll
        for (int mi = 0; mi < 4; ++mi) {
            f32x4 v = pacc[i][mi];
#pragma unroll
            for (int r = 0; r < 4; ++r) {
                int n = mi * 16 + lg * 4 + r;
                if (n < 49) ob[n * 384 + c] = v[r] + bias;
            }
        }
    }
}

extern "C" void kernel_launch(void* const* d_in, const int* in_sizes, int n_in,
                              void* d_out, int out_size, void* d_ws, size_t ws_size,
                              hipStream_t stream) {
    const float* x      = (const float*)d_in[0];
    const float* qw     = (const float*)d_in[1];
    const float* qb     = (const float*)d_in[2];
    const float* kw     = (const float*)d_in[3];
    const float* kb     = (const float*)d_in[4];
    const float* vw     = (const float*)d_in[5];
    const float* vb     = (const float*)d_in[6];
    const float* pw     = (const float*)d_in[7];
    const float* pb     = (const float*)d_in[8];
    const float* biases = (const float*)d_in[9];
    const int*   idxs   = (const int*)d_in[10];
    int n_off = in_sizes[9] / HEADS;

    char* ws = (char*)d_ws;
    unsigned short* qk_p = (unsigned short*)ws;                    // 393216 B
    unsigned short* vw_p = (unsigned short*)(ws + 393216);         // 786432 B
    unsigned short* pw_p = (unsigned short*)(ws + 1179648);        // 786432 B
    float*          qb_s = (float*)(ws + 1966080);                 // 1024 B
    float*          ab_t = (float*)(ws + 1967104);                 // 131072 B

    prologue<<<609, 256, 0, stream>>>(qw, qb, kw, vw, pw, biases, idxs, n_off,
                                      qk_p, vw_p, pw_p, qb_s, ab_t);
    fused_attn<<<2048, 512, 0, stream>>>(x, qk_p, vw_p, pw_p, qb_s, kb, vb, pb,
                                         ab_t, (float*)d_out);
}

// Round 4
// 453.563 us; speedup vs baseline: 1.7156x; 1.7156x over previous
//
#include <hip/hip_runtime.h>
#include <hip/hip_bf16.h>

#define NTOK   49
#define DIM    384
#define KEY_DIM 32
#define HEADS  8
#define D_HEAD 128
#define SCALE  0.17677669529663687f   // 32^-0.5

typedef short short8 __attribute__((ext_vector_type(8)));
typedef short short4_t __attribute__((ext_vector_type(4)));
typedef float f32x4 __attribute__((ext_vector_type(4)));

__device__ __forceinline__ unsigned short f2bf(float x) {
    union { float f; unsigned u; } v; v.f = x;
    unsigned r = v.u + 0x7fffu + ((v.u >> 16) & 1u);   // RNE
    return (unsigned short)(r >> 16);
}

__device__ __forceinline__ f32x4 MFMA(short8 a, short8 b, f32x4 c) {
    return __builtin_amdgcn_mfma_f32_16x16x32_bf16(a, b, c, 0, 0, 0);
}

// ---------------- prologue: weight packing + bias expansion ----------------
// packed chunk layout for weight W[N][K] (row-major, K contig):
//   chunk t = (ntile*KT + ktile)*64 + lane ; elem j: W[ntile*16+(lane&15)][ktile*32+(lane>>4)*8+j]
__global__ void prologue(const float* __restrict__ qw, const float* __restrict__ qb,
                         const float* __restrict__ kw,
                         const float* __restrict__ vw, const float* __restrict__ pw,
                         const float* __restrict__ biases, const int* __restrict__ idxs,
                         int n_off,
                         unsigned short* __restrict__ qk_p,
                         unsigned short* __restrict__ vw_p,
                         unsigned short* __restrict__ pw_p,
                         float* __restrict__ qb_s,
                         float* __restrict__ ab_t) {
    int t = blockIdx.x * 256 + threadIdx.x;
    if (t < 24576) {                       // QK pack: N=512 (Q|K), K=384, KT=12
        int lane = t & 63, kt = (t >> 6) % 12, ntile = t / 768;
        int c = ntile * 16 + (lane & 15), kk = kt * 32 + (lane >> 4) * 8;
        const float* src = (c < 256) ? (qw + c * 384 + kk) : (kw + (c - 256) * 384 + kk);
        float sc = (c < 256) ? SCALE : 1.0f;
        short8 o;
#pragma unroll
        for (int j = 0; j < 8; ++j) o[j] = (short)f2bf(src[j] * sc);
        *(short8*)(qk_p + (size_t)t * 8) = o;
    } else if (t < 73728) {                // V pack: N=1024, K=384, KT=12
        int u = t - 24576;
        int lane = u & 63, kt = (u >> 6) % 12, ntile = u / 768;
        int c = ntile * 16 + (lane & 15), kk = kt * 32 + (lane >> 4) * 8;
        const float* src = vw + c * 384 + kk;
        short8 o;
#pragma unroll
        for (int j = 0; j < 8; ++j) o[j] = (short)f2bf(src[j]);
        *(short8*)(vw_p + (size_t)u * 8) = o;
    } else if (t < 122880) {               // proj pack: N=384, K=1024, KT=32
        int u = t - 73728;
        int lane = u & 63, kt = (u >> 6) % 32, ntile = u / 2048;
        int c = ntile * 16 + (lane & 15), kk = kt * 32 + (lane >> 4) * 8;
        const float* src = pw + c * 1024 + kk;
        short8 o;
#pragma unroll
        for (int j = 0; j < 8; ++j) o[j] = (short)f2bf(src[j]);
        *(short8*)(pw_p + (size_t)u * 8) = o;
    } else if (t < 123136) {               // scaled q bias
        int u = t - 122880;
        qb_s[u] = qb[u] * SCALE;
    } else if (t < 123136 + 32768) {       // ab_t[h][n][m] (n=query, m=key), zero-padded 64x64
        int u = t - 123136;
        int h = u >> 12, n = (u >> 6) & 63, m = u & 63;
        float v = 0.f;
        if (m < 49 && n < 49) v = biases[h * n_off + idxs[n * 49 + m]];
        ab_t[u] = v;
    }
}

// ---------------- fused attention: one block (8 waves) per batch ----------------
// LDS layout (ushort offsets), total 81,312 B -> 2 blocks/CU (LDS-limited):
//   xs  @     0 : [49][392]   x bf16 (A-row reads clamp to row 48)
//   ps  @ 19208 : [49][72]    P bf16 (writes predicated n<49, reads clamped)
//   vsT @ 22736 : [128][72]   V_h^T [d][m]
//   U   @ 31952 : 17,408 B union:
//        qs  = U          [64][40]   (live P0 -> bar B)
//        ks2 = U + 2560   [64][40]
//        osA = U          [64][136]  (live bar B -> bar D)
__global__ __launch_bounds__(512) void fused_attn(
        const float* __restrict__ x,
        const unsigned short* __restrict__ qkw,   // packed [32 nt][12 kt][64][8]
        const unsigned short* __restrict__ vw,    // packed [64 nt][12 kt][64][8]
        const unsigned short* __restrict__ pw,    // packed [24 nt][32 kt][64][8]
        const float* __restrict__ qb_s, const float* __restrict__ kb,
        const float* __restrict__ vb, const float* __restrict__ pb,
        const float* __restrict__ ab_t,           // [8][64 n][64 m] f32
        float* __restrict__ out) {

    __shared__ __align__(16) unsigned short smem[40656];   // 81,312 B
    unsigned short* xs  = smem;              // [49][392]
    unsigned short* ps  = smem + 19208;      // [49][72]
    unsigned short* vsT = smem + 22736;      // [128][72]
    unsigned short* qs  = smem + 31952;      // [64][40]
    unsigned short* ks2 = smem + 31952 + 2560; // [64][40]
    unsigned short* osA = smem + 31952;      // [64][136] overlays qs/ks2

    const int tid  = threadIdx.x;
    const int lane = tid & 63;
    const int wid  = tid >> 6;       // 0..7
    const int l15  = lane & 15;
    const int lg   = lane >> 4;      // 0..3
    const int b    = blockIdx.x;

    // ---- stage x -> bf16 LDS (49 rows only; reads clamp). NT: x is touch-once ----
    const float* xb = x + (size_t)b * (NTOK * DIM);
#pragma unroll 2
    for (int i = tid; i < 4704; i += 512) {            // 4704 float4
        f32x4 v = __builtin_nontemporal_load(((const f32x4*)xb) + i);
        int f = i * 4;
        int row = f / DIM;
        int col = f - row * DIM;
        short4_t pk;
        pk[0] = (short)f2bf(v[0]); pk[1] = (short)f2bf(v[1]);
        pk[2] = (short)f2bf(v[2]); pk[3] = (short)f2bf(v[3]);
        *(short4_t*)&xs[row * 392 + col] = pk;
    }
    __syncthreads();

    f32x4 pacc[3][4];                                   // persistent proj acc
#pragma unroll
    for (int i = 0; i < 3; ++i)
#pragma unroll
        for (int j = 0; j < 4; ++j) pacc[i][j] = (f32x4)0.f;

    const f32x4 zf = (f32x4)0.f;

    for (int h = 0; h < HEADS; ++h) {
        // ================= P0: Q_h,K_h,V_h projection =================
        {
            const int mh  = wid >> 2;          // 0..1 -> rows mh*32..mh*32+31
            const int nt0 = 3 * (wid & 3);     // nt triple, N=192 = 12 nt
            const int rA0 = min(mh * 32 + l15, 48);
            const int rA1 = min(mh * 32 + 16 + l15, 48);
            f32x4 acc[3][2];
#pragma unroll
            for (int i = 0; i < 3; ++i) { acc[i][0] = zf; acc[i][1] = zf; }

            const short8* bptr[3];
#pragma unroll
            for (int i = 0; i < 3; ++i) {
                int nt = nt0 + i;
                const unsigned short* base; int ntile;
                if (nt < 2)      { base = qkw; ntile = 2 * h + nt; }
                else if (nt < 4) { base = qkw; ntile = 16 + 2 * h + (nt - 2); }
                else             { base = vw;  ntile = 8 * h + (nt - 4); }
                bptr[i] = (const short8*)(base + (size_t)ntile * 12 * 64 * 8);
            }
#pragma unroll
            for (int kt = 0; kt < 12; ++kt) {
                short8 a0 = *(const short8*)&xs[rA0 * 392 + kt * 32 + lg * 8];
                short8 a1 = *(const short8*)&xs[rA1 * 392 + kt * 32 + lg * 8];
#pragma unroll
                for (int i = 0; i < 3; ++i) {
                    short8 bf = bptr[i][kt * 64 + lane];
                    acc[i][0] = MFMA(a0, bf, acc[i][0]);
                    acc[i][1] = MFMA(a1, bf, acc[i][1]);
                }
            }
            // epilogue: +bias, ->bf16, scatter to qs/ks/vsT
#pragma unroll
            for (int i = 0; i < 3; ++i) {
                int nt = nt0 + i;
                int c  = nt * 16 + l15;        // 0..191
                if (nt < 4) {                  // Q (c<32) or K (32..63)
                    int cc = (nt < 2) ? c : c - 32;
                    float bias = (nt < 2) ? qb_s[h * 32 + cc] : kb[h * 32 + cc];
                    unsigned short* dst = (nt < 2) ? qs : ks2;
#pragma unroll
                    for (int j = 0; j < 2; ++j) {
                        int r0 = mh * 32 + j * 16 + lg * 4;
                        f32x4 v = acc[i][j];
#pragma unroll
                        for (int r = 0; r < 4; ++r)
                            dst[(r0 + r) * 40 + cc] = f2bf(v[r] + bias);
                    }
                } else {                       // V -> transposed
                    int d = c - 64;            // 0..127
                    float bias = vb[h * 128 + d];
#pragma unroll
                    for (int j = 0; j < 2; ++j) {
                        int m0 = mh * 32 + j * 16 + lg * 4;
                        f32x4 v = acc[i][j];
                        short4_t pk;
#pragma unroll
                        for (int r = 0; r < 4; ++r) pk[r] = (short)f2bf(v[r] + bias);
                        *(short4_t*)&vsT[d * 72 + m0] = pk;
                    }
                }
            }
        }
        __syncthreads();   // bar A: qs/ks/vsT ready

        // ================= P1: S^T = K@Q^T, softmax (waves 0-3) =================
        if (wid < 4) {
            const int I = wid;                 // n-tile (query tile)
            const int rq = min(I * 16 + l15, 48);
            short8 bq = *(const short8*)&qs[rq * 40 + lg * 8];
            f32x4 s[4];
#pragma unroll
            for (int J = 0; J < 4; ++J) {
                short8 ak = *(const short8*)&ks2[(J * 16 + l15) * 40 + lg * 8];
                s[J] = MFMA(ak, bq, zf);
            }
            // coalesced bias: ab_t[h][n][m], lane reads 4x float4 along m
            const f32x4* abn = (const f32x4*)(ab_t + ((h * 64 + I * 16 + l15) * 64));
            float sv[16];
            float mx = -1e30f;
#pragma unroll
            for (int J = 0; J < 4; ++J) {
                f32x4 a4 = abn[J * 4 + lg];
#pragma unroll
                for (int r = 0; r < 4; ++r) {
                    int m = J * 16 + lg * 4 + r;
                    float val = s[J][r] + a4[r];
                    if (m >= 49) val = -1e30f;
                    sv[J * 4 + r] = val;
                    mx = fmaxf(mx, val);
                }
            }
            mx = fmaxf(mx, __shfl_xor(mx, 16));
            mx = fmaxf(mx, __shfl_xor(mx, 32));
            float sum = 0.f;
#pragma unroll
            for (int t = 0; t < 16; ++t) { float e = __expf(sv[t] - mx); sv[t] = e; sum += e; }
            sum += __shfl_xor(sum, 16);
            sum += __shfl_xor(sum, 32);
            float inv = 1.0f / sum;
            int n = I * 16 + l15;
            if (n < 49) {
#pragma unroll
                for (int J = 0; J < 4; ++J)
#pragma unroll
                    for (int r = 0; r < 4; ++r) {
                        int m = J * 16 + lg * 4 + r;
                        ps[n * 72 + m] = f2bf(sv[J * 4 + r] * inv);
                    }
            }
        }
        __syncthreads();   // bar B: ps ready (qs/ks dead -> osA may be written)

        // ================= P2a: O_h = P @ V_h =================
        {
            const int np = wid >> 2;           // n-tile pair
            const int dp = wid & 3;            // d-tile pair
            const int rp0 = min(np * 32 + l15, 48);
            const int rp1 = min(np * 32 + 16 + l15, 48);
            f32x4 a00 = zf, a01 = zf, a10 = zf, a11 = zf;
#pragma unroll
            for (int kk = 0; kk < 2; ++kk) {
                short8 a0 = *(const short8*)&ps[rp0 * 72 + kk * 32 + lg * 8];
                short8 a1 = *(const short8*)&ps[rp1 * 72 + kk * 32 + lg * 8];
                short8 b0 = *(const short8*)&vsT[(dp * 32 + l15) * 72 + kk * 32 + lg * 8];
                short8 b1 = *(const short8*)&vsT[(dp * 32 + 16 + l15) * 72 + kk * 32 + lg * 8];
                a00 = MFMA(a0, b0, a00); a01 = MFMA(a0, b1, a01);
                a10 = MFMA(a1, b0, a10); a11 = MFMA(a1, b1, a11);
            }
            f32x4 accs[2][2] = {{a00, a01}, {a10, a11}};
#pragma unroll
            for (int jn = 0; jn < 2; ++jn)
#pragma unroll
                for (int jd = 0; jd < 2; ++jd) {
                    int r0 = np * 32 + jn * 16 + lg * 4;
                    int d0 = dp * 32 + jd * 16 + l15;
                    f32x4 v = accs[jn][jd];
#pragma unroll
                    for (int r = 0; r < 4; ++r) osA[(r0 + r) * 136 + d0] = f2bf(v[r]);
                }
        }
        __syncthreads();   // bar C: osA ready

        // ================= P2b: out-proj chunk (K = this head's 128) =================
        {
            const int nt0 = 3 * wid;           // 24 nt over 8 waves
#pragma unroll
            for (int kt = 0; kt < 4; ++kt) {
                short8 a[4];
#pragma unroll
                for (int mi = 0; mi < 4; ++mi)
                    a[mi] = *(const short8*)&osA[(mi * 16 + l15) * 136 + kt * 32 + lg * 8];
#pragma unroll
                for (int i = 0; i < 3; ++i) {
                    short8 bf = ((const short8*)pw)[((size_t)(nt0 + i) * 32 + (h * 4 + kt)) * 64 + lane];
#pragma unroll
                    for (int mi = 0; mi < 4; ++mi)
                        pacc[i][mi] = MFMA(a[mi], bf, pacc[i][mi]);
                }
            }
        }
        __syncthreads();   // bar D: safe to overwrite qs/ks/vsT/ps/osA
    }

    // ---- final epilogue: +proj_b, store f32 rows n<49 (NT: touch-once stream) ----
    float* ob = out + (size_t)b * (NTOK * 384);
#pragma unroll
    for (int i = 0; i < 3; ++i) {
        int c = (3 * wid + i) * 16 + l15;
        float bias = pb[c];
#pragma unroll
        for (int mi = 0; mi < 4; ++mi) {
            f32x4 v = pacc[i][mi];
#pragma unroll
            for (int r = 0; r < 4; ++r) {
                int n = mi * 16 + lg * 4 + r;
                if (n < 49) __builtin_nontemporal_store(v[r] + bias, &ob[n * 384 + c]);
            }
        }
    }
}

extern "C" void kernel_launch(void* const* d_in, const int* in_sizes, int n_in,
                              void* d_out, int out_size, void* d_ws, size_t ws_size,
                              hipStream_t stream) {
    const float* x      = (const float*)d_in[0];
    const float* qw     = (const float*)d_in[1];
    const float* qb     = (const float*)d_in[2];
    const float* kw     = (const float*)d_in[3];
    const float* kb     = (const float*)d_in[4];
    const float* vw     = (const float*)d_in[5];
    const float* vb     = (const float*)d_in[6];
    const float* pw     = (const float*)d_in[7];
    const float* pb     = (const float*)d_in[8];
    const float* biases = (const float*)d_in[9];
    const int*   idxs   = (const int*)d_in[10];
    int n_off = in_sizes[9] / HEADS;

    char* ws = (char*)d_ws;
    unsigned short* qk_p = (unsigned short*)ws;                    // 393216 B
    unsigned short* vw_p = (unsigned short*)(ws + 393216);         // 786432 B
    unsigned short* pw_p = (unsigned short*)(ws + 1179648);        // 786432 B
    float*          qb_s = (float*)(ws + 1966080);                 // 1024 B
    float*          ab_t = (float*)(ws + 1967104);                 // 131072 B

    prologue<<<609, 256, 0, stream>>>(qw, qb, kw, vw, pw, biases, idxs, n_off,
                                      qk_p, vw_p, pw_p, qb_s, ab_t);
    fused_attn<<<2048, 512, 0, stream>>>(x, qk_p, vw_p, pw_p, qb_s, kb, vb, pb,
                                         ab_t, (float*)d_out);
}